// Round 16
// baseline (70.019 us; speedup 1.0000x reference)
//
#include <hip/hip_runtime.h>

#define NPTS 65536

__device__ __forceinline__ float bf_lo(unsigned u) { return __uint_as_float(u << 16); }
__device__ __forceinline__ float bf_hi(unsigned u) { return __uint_as_float(u & 0xFFFF0000u); }
__device__ __forceinline__ unsigned short f2bf(float f) {      // RNE round
    unsigned u = __float_as_uint(f);
    return (unsigned short)((u + 0x7FFFu + ((u >> 16) & 1u)) >> 16);
}
__device__ __forceinline__ float bfu(unsigned short us) {
    return __uint_as_float(((unsigned)us) << 16);
}
__device__ __forceinline__ unsigned pktrunc(float a, float b) { // truncate pair pack
    return (__float_as_uint(a) >> 16) | (__float_as_uint(b) & 0xFFFF0000u);
}
#if __has_builtin(__builtin_amdgcn_fdot2_f32_bf16)
typedef __bf16 bf16x2 __attribute__((ext_vector_type(2)));
__device__ __forceinline__ float dot2acc(unsigned a, unsigned b, float c) {
    return __builtin_amdgcn_fdot2_f32_bf16(__builtin_bit_cast(bf16x2, a),
                                           __builtin_bit_cast(bf16x2, b), c, false);
}
#else
__device__ __forceinline__ float dot2acc(unsigned a, unsigned b, float c) {
    return c + bf_lo(a) * bf_lo(b) + bf_hi(a) * bf_hi(b);
}
#endif
#if __has_builtin(__builtin_amdgcn_rcpf)
__device__ __forceinline__ float fastrcp(float x) { return __builtin_amdgcn_rcpf(x); }
#else
__device__ __forceinline__ float fastrcp(float x) { return 1.0f / x; }
#endif

// ---- fp8 e4m3 pack/unpack (HW cvt — presence proven by R15 bench) ----------
typedef float floatx2 __attribute__((ext_vector_type(2)));
__device__ __forceinline__ void unpk_fp8_u32(unsigned u, float* o) {
    floatx2 lo = __builtin_amdgcn_cvt_pk_f32_fp8((int)u, false);
    floatx2 hi = __builtin_amdgcn_cvt_pk_f32_fp8((int)u, true);
    o[0] = lo[0]; o[1] = lo[1]; o[2] = hi[0]; o[3] = hi[1];
}
__device__ __forceinline__ unsigned pk_fp8_4(float a, float b, float c, float d) {
    int v = __builtin_amdgcn_cvt_pk_fp8_f32(a, b, 0, false);
    v = __builtin_amdgcn_cvt_pk_fp8_f32(c, d, v, true);
    return (unsigned)v;
}
__device__ __forceinline__ unsigned short pk_fp8_2(float a, float b) {
    return (unsigned short)((unsigned)__builtin_amdgcn_cvt_pk_fp8_f32(a, b, 0, false) & 0xFFFFu);
}

typedef __attribute__((ext_vector_type(8))) short short8;     // bf16x8 frag
typedef __attribute__((ext_vector_type(4))) float f32x4;      // acc frag

// -------- Kernel 1: Mt[which][e][c] = bf16((WQ^T WK)[c][e]); WVb = bf16(WV) --
__global__ __launch_bounds__(256) void k_matM(const float* __restrict__ WQa,
                                              const float* __restrict__ WKa,
                                              const float* __restrict__ WQe,
                                              const float* __restrict__ WKe,
                                              const float* __restrict__ WVa,
                                              const float* __restrict__ WVe,
                                              unsigned short* __restrict__ Mt,
                                              unsigned short* __restrict__ WVb) {
    const int t = threadIdx.x;
    if (blockIdx.x >= 8) {            // WV -> bf16 table
        const int which = blockIdx.x - 8;
        const float* WV = which ? WVe : WVa;
        unsigned short* dst = WVb + which * 4096;
        #pragma unroll
        for (int i = 0; i < 16; ++i) dst[t + i * 256] = f2bf(WV[t + i * 256]);
        return;
    }
    __shared__ float WKs[4096];       // full WK, row-major [d][e]
    __shared__ float WQs[64][16];     // WQ columns c0..c0+15
    const int which = blockIdx.x >> 2;
    const int c0 = (blockIdx.x & 3) * 16;
    const float* WQ = which ? WQe : WQa;
    const float* WK = which ? WKe : WKa;
    #pragma unroll
    for (int i = 0; i < 16; ++i) WKs[t + i * 256] = WK[t + i * 256];
    #pragma unroll
    for (int i = 0; i < 4; ++i) {
        const int id = t + i * 256;
        WQs[id >> 4][id & 15] = WQ[(id >> 4) * 64 + c0 + (id & 15)];
    }
    __syncthreads();
    const int cc = t >> 4;            // c = c0+cc
    const int eg = t & 15;            // e = eg*4 + j
    float a0 = 0.f, a1 = 0.f, a2 = 0.f, a3 = 0.f;
    #pragma unroll
    for (int d = 0; d < 64; ++d) {
        const float wq = WQs[d][cc];
        const float4 wk = *reinterpret_cast<const float4*>(&WKs[d * 64 + eg * 4]);
        a0 += wq * wk.x; a1 += wq * wk.y; a2 += wq * wk.z; a3 += wq * wk.w;
    }
    const int c = c0 + cc;
    Mt[which * 4096 + (eg * 4 + 0) * 64 + c] = f2bf(a0);
    Mt[which * 4096 + (eg * 4 + 1) * 64 + c] = f2bf(a1);
    Mt[which * 4096 + (eg * 4 + 2) * 64 + c] = f2bf(a2);
    Mt[which * 4096 + (eg * 4 + 3) * 64 + c] = f2bf(a3);
}

// -------- Kernel 2: pack featT bf16 + featQ fp8 + qeff fp8 via MFMA GEMM -----
__global__ __launch_bounds__(256) void k_prep(const float* __restrict__ spa,
                                              const float* __restrict__ spe,
                                              const unsigned short* __restrict__ Mt,
                                              unsigned short* __restrict__ featT,
                                              unsigned char* __restrict__ featQ,
                                              unsigned char* __restrict__ qeff8) {
    __shared__ unsigned short tb[64][136];   // 17408 B
    __shared__ unsigned short ml[2][64][72]; // 18432 B
    const int n0 = blockIdx.x * 64;
    const int t = threadIdx.x;
    // ---- phase 0: stage Mt (16 KB) into LDS
    #pragma unroll
    for (int i = 0; i < 4; ++i) {
        const int id = t + i * 256;
        const int which = id >> 9;
        const int row = (id >> 3) & 63;
        const int q = id & 7;
        *reinterpret_cast<uint4*>(&ml[which][row][q * 8]) =
            *reinterpret_cast<const uint4*>(Mt + which * 4096 + row * 64 + q * 8);
    }
    // ---- phase 1: coalesced column loads -> bf16 tile, channel-PAIR packed
    {
        const int p = t & 63;
        const int c0 = 2 * (t >> 6);          // 0,2,4,6
        #pragma unroll
        for (int i = 0; i < 16; ++i) {
            const int c = c0 + 8 * i;
            const float v0 = (c < 64) ? spa[c * NPTS + n0 + p]
                                      : spe[(c - 64) * NPTS + n0 + p];
            const float v1 = (c + 1 < 64) ? spa[(c + 1) * NPTS + n0 + p]
                                          : spe[(c + 1 - 64) * NPTS + n0 + p];
            *reinterpret_cast<unsigned*>(&tb[p][c]) =
                (unsigned)f2bf(v0) | ((unsigned)f2bf(v1) << 16);
        }
    }
    __syncthreads();
    // ---- phase 2: featT (bf16) + featQ (fp8) writeback
    {
        const int pt = t >> 2;
        const int q = t & 3;
        const uint4* src = reinterpret_cast<const uint4*>(&tb[pt][q * 32]);
        const uint4 s0 = src[0], s1 = src[1], s2 = src[2], s3 = src[3];
        uint4* dst = reinterpret_cast<uint4*>(featT + (size_t)(n0 + pt) * 128 + q * 32);
        dst[0] = s0; dst[1] = s1; dst[2] = s2; dst[3] = s3;
        unsigned o0 = pk_fp8_4(bf_lo(s0.x), bf_hi(s0.x), bf_lo(s0.y), bf_hi(s0.y));
        unsigned o1 = pk_fp8_4(bf_lo(s0.z), bf_hi(s0.z), bf_lo(s0.w), bf_hi(s0.w));
        unsigned o2 = pk_fp8_4(bf_lo(s1.x), bf_hi(s1.x), bf_lo(s1.y), bf_hi(s1.y));
        unsigned o3 = pk_fp8_4(bf_lo(s1.z), bf_hi(s1.z), bf_lo(s1.w), bf_hi(s1.w));
        unsigned o4 = pk_fp8_4(bf_lo(s2.x), bf_hi(s2.x), bf_lo(s2.y), bf_hi(s2.y));
        unsigned o5 = pk_fp8_4(bf_lo(s2.z), bf_hi(s2.z), bf_lo(s2.w), bf_hi(s2.w));
        unsigned o6 = pk_fp8_4(bf_lo(s3.x), bf_hi(s3.x), bf_lo(s3.y), bf_hi(s3.y));
        unsigned o7 = pk_fp8_4(bf_lo(s3.z), bf_hi(s3.z), bf_lo(s3.w), bf_hi(s3.w));
        uint4* qd = reinterpret_cast<uint4*>(featQ + (size_t)(n0 + pt) * 128 + q * 32);
        qd[0] = make_uint4(o0, o1, o2, o3);
        qd[1] = make_uint4(o4, o5, o6, o7);
    }
    // ---- phase 3: qeff GEMM via MFMA, fp8 output
    const int w = t >> 6;
    const int l = t & 63;
    const int lrow = l & 15;
    const int lk8 = (l >> 4) * 8;
    short8 afr[2][2];
    #pragma unroll
    for (int half = 0; half < 2; ++half)
        #pragma unroll
        for (int kc = 0; kc < 2; ++kc)
            afr[half][kc] = __builtin_bit_cast(short8,
                *reinterpret_cast<const uint4*>(&tb[w * 16 + lrow][half * 64 + kc * 32 + lk8]));
    f32x4 acc[8];
    #pragma unroll
    for (int et = 0; et < 8; ++et) acc[et] = (f32x4){0.f, 0.f, 0.f, 0.f};
    #pragma unroll
    for (int et = 0; et < 8; ++et) {
        const int which = et >> 2;
        const int el = (et & 3) * 16 + lrow;
        #pragma unroll
        for (int kc = 0; kc < 2; ++kc) {
            const short8 bfr = __builtin_bit_cast(short8,
                *reinterpret_cast<const uint4*>(&ml[which][el][kc * 32 + lk8]));
            acc[et] = __builtin_amdgcn_mfma_f32_16x16x32_bf16(afr[which][kc], bfr, acc[et], 0, 0, 0);
        }
    }
    #pragma unroll
    for (int et = 0; et < 8; ++et) {
        #pragma unroll
        for (int r = 0; r < 4; ++r) {
            const int n = n0 + w * 16 + (l >> 4) * 4 + r;
            const unsigned v = (unsigned)__builtin_amdgcn_cvt_pk_fp8_f32(acc[et][r], acc[et][r], 0, false);
            qeff8[(size_t)n * 128 + et * 16 + lrow] = (unsigned char)(v & 0xFF);
        }
    }
}

// ---------------- Kernel 3: attention (1 wave = 1 point, lane = k*4+c4) ------
__global__ __launch_bounds__(256) void k_attn(const unsigned char* __restrict__ featQ,
                                              const unsigned char* __restrict__ qeff8,
                                              const int* __restrict__ idx,
                                              unsigned char* __restrict__ sTb8) {
    __shared__ unsigned red[4][16][68];   // 17408 B
    const int wave = threadIdx.x >> 6;
    const int lane = threadIdx.x & 63;
    const int n = blockIdx.x * 4 + wave;
    const int k = lane >> 2;          // neighbor owned by this lane
    const int c4 = lane & 3;          // channel quarter (16 channels)

    const int j = idx[n * 16 + k];    // 4 lanes same addr -> broadcast
    float xa[16], xe[16];
    unsigned bxa[8], bxe[8];          // packed bf16 pairs for dot2 scores
    {
        const uint4* fq = reinterpret_cast<const uint4*>(featQ + (size_t)j * 128);
        const uint4 FA = fq[c4], FE = fq[4 + c4];      // 16 fp8 each
        unpk_fp8_u32(FA.x, xa);      unpk_fp8_u32(FA.y, xa + 4);
        unpk_fp8_u32(FA.z, xa + 8);  unpk_fp8_u32(FA.w, xa + 12);
        unpk_fp8_u32(FE.x, xe);      unpk_fp8_u32(FE.y, xe + 4);
        unpk_fp8_u32(FE.z, xe + 8);  unpk_fp8_u32(FE.w, xe + 12);
        #pragma unroll
        for (int i = 0; i < 8; ++i) {     // exact: fp8 mantissa fits bf16
            bxa[i] = pktrunc(xa[2*i], xa[2*i + 1]);
            bxe[i] = pktrunc(xe[2*i], xe[2*i + 1]);
        }
    }
    unsigned bqa[8], bqe[8];
    {
        const uint4* qx = reinterpret_cast<const uint4*>(qeff8 + (size_t)n * 128);
        const uint4 QA = qx[c4], QE = qx[4 + c4];
        float qa[16], qe[16];
        unpk_fp8_u32(QA.x, qa);      unpk_fp8_u32(QA.y, qa + 4);
        unpk_fp8_u32(QA.z, qa + 8);  unpk_fp8_u32(QA.w, qa + 12);
        unpk_fp8_u32(QE.x, qe);      unpk_fp8_u32(QE.y, qe + 4);
        unpk_fp8_u32(QE.z, qe + 8);  unpk_fp8_u32(QE.w, qe + 12);
        #pragma unroll
        for (int i = 0; i < 8; ++i) {
            bqa[i] = pktrunc(qa[2*i], qa[2*i + 1]);
            bqe[i] = pktrunc(qe[2*i], qe[2*i + 1]);
        }
    }

    // scores: spa att = q_spa . x_spe ; spe att = q_spe . x_spa
    float pa = 0.f, pe = 0.f;
    #pragma unroll
    for (int i = 0; i < 8; ++i) {
        pa = dot2acc(bqa[i], bxe[i], pa);
        pe = dot2acc(bqe[i], bxa[i], pe);
    }
    pa += __shfl_xor(pa, 1); pa += __shfl_xor(pa, 2);   // reduce over c4
    pe += __shfl_xor(pe, 1); pe += __shfl_xor(pe, 2);
    // |score| small by construction -> exp w/o max-sub
    const float ea = __expf(pa * 0.125f);
    const float ee = __expf(pe * 0.125f);
    float da = ea, de = ee;
    #pragma unroll
    for (int m = 4; m < 64; m <<= 1) {  // sum over the 16 k, each once
        da += __shfl_xor(da, m);
        de += __shfl_xor(de, m);
    }
    const float wA = ea * fastrcp(da);
    const float wB = ee * fastrcp(de);

    // packed truncate-to-bf16 pairs; col j = channels (2j, 2j+1)
    unsigned pA[8], pB[8];
    #pragma unroll
    for (int i = 0; i < 8; ++i) {
        pA[i] = pktrunc(wA * xe[2*i], wA * xe[2*i + 1]);   // ctx_spa from spe
        pB[i] = pktrunc(wB * xa[2*i], wB * xa[2*i + 1]);   // ctx_spe from spa
    }
    {
        uint4* wa4 = reinterpret_cast<uint4*>(&red[wave][k][c4 * 8]);
        wa4[0] = make_uint4(pA[0], pA[1], pA[2], pA[3]);
        wa4[1] = make_uint4(pA[4], pA[5], pA[6], pA[7]);
        uint4* wb4 = reinterpret_cast<uint4*>(&red[wave][k][32 + c4 * 8]);
        wb4[0] = make_uint4(pB[0], pB[1], pB[2], pB[3]);
        wb4[1] = make_uint4(pB[4], pB[5], pB[6], pB[7]);
    }
    asm volatile("s_waitcnt lgkmcnt(0)" ::: "memory");  // wave-internal fence
    float s0 = 0.f, s1 = 0.f;
    #pragma unroll
    for (int kk = 0; kk < 16; ++kk) {
        const unsigned v = red[wave][kk][lane];
        s0 += __uint_as_float(v << 16);
        s1 += __uint_as_float(v & 0xFFFF0000u);
    }
    // fp8 pair store: bytes (2*lane, 2*lane+1) of row n -> coalesced 128B/wave
    reinterpret_cast<unsigned short*>(sTb8 + (size_t)n * 128)[lane] = pk_fp8_2(s0, s1);
}

// ---------------- Kernel 4: ctx = WV*s + b via MFMA, + residual, write -------
__global__ __launch_bounds__(256, 4) void k_out(const unsigned char* __restrict__ sTb8,
                                                const unsigned short* __restrict__ featT,
                                                const unsigned short* __restrict__ WVb,
                                                const float* __restrict__ bVa,
                                                const float* __restrict__ bVe,
                                                float* __restrict__ out) {
    __shared__ char smem_raw[27136];
    unsigned short* stile = reinterpret_cast<unsigned short*>(smem_raw);         // [32][136]
    unsigned short* wvl = reinterpret_cast<unsigned short*>(smem_raw + 8704);    // [2][64][72]
    float* ctxT = reinterpret_cast<float*>(smem_raw);                            // [128][33] overlay
    const int n0 = blockIdx.x * 32;
    const int t = threadIdx.x;
    const int w = t >> 6;
    const int l = t & 63;
    const int half = w >> 1;
    const int pg = w & 1;
    const int lrow = l & 15;
    const int lk8 = (l >> 4) * 8;
    unsigned short res[4][4];
    #pragma unroll
    for (int nt = 0; nt < 4; ++nt)
        #pragma unroll
        for (int r = 0; r < 4; ++r) {
            const int pt = pg * 16 + (l >> 4) * 4 + r;
            res[nt][r] = featT[(size_t)(n0 + pt) * 128 + half * 64 + nt * 16 + lrow];
        }
    // ---- stage s-tile: fp8 -> bf16 (256 threads cover 32 rows x 8 quads) ----
    {
        const int pt = t >> 3;            // 0..31
        const int q = t & 7;              // 16B of fp8 = 16 values
        const uint4 v = *reinterpret_cast<const uint4*>(sTb8 + (size_t)(n0 + pt) * 128 + q * 16);
        float f[16];
        unpk_fp8_u32(v.x, f);      unpk_fp8_u32(v.y, f + 4);
        unpk_fp8_u32(v.z, f + 8);  unpk_fp8_u32(v.w, f + 12);
        unsigned* d = reinterpret_cast<unsigned*>(stile + pt * 136 + q * 16);
        #pragma unroll
        for (int i = 0; i < 8; ++i) d[i] = pktrunc(f[2*i], f[2*i + 1]);
    }
    // ---- stage WVb (16 KB bf16): 1024 uint4s coalesced ----
    #pragma unroll
    for (int i = 0; i < 4; ++i) {
        const int id = t + i * 256;
        const int which = id >> 9;
        const int row = (id >> 3) & 63;
        const int q = id & 7;
        *reinterpret_cast<uint4*>(wvl + which * 4608 + row * 72 + q * 8) =
            *reinterpret_cast<const uint4*>(WVb + which * 4096 + row * 64 + q * 8);
    }
    __syncthreads();
    short8 afr[2];
    #pragma unroll
    for (int kc = 0; kc < 2; ++kc)
        afr[kc] = __builtin_bit_cast(short8,
            *reinterpret_cast<const uint4*>(stile + (pg * 16 + lrow) * 136 + half * 64 + kc * 32 + lk8));
    const unsigned short* wt = wvl + half * 4608;
    const float* bV = half ? bVe : bVa;
    f32x4 acc[4];
    #pragma unroll
    for (int nt = 0; nt < 4; ++nt) {
        acc[nt] = (f32x4){0.f, 0.f, 0.f, 0.f};
        #pragma unroll
        for (int kc = 0; kc < 2; ++kc) {
            const short8 bfr = __builtin_bit_cast(short8,
                *reinterpret_cast<const uint4*>(wt + (nt * 16 + lrow) * 72 + kc * 32 + lk8));
            acc[nt] = __builtin_amdgcn_mfma_f32_16x16x32_bf16(afr[kc], bfr, acc[nt], 0, 0, 0);
        }
    }
    __syncthreads();
    #pragma unroll
    for (int nt = 0; nt < 4; ++nt) {
        const int d = nt * 16 + lrow;
        const int dglob = half * 64 + d;
        const float bias = bV[d];
        #pragma unroll
        for (int r = 0; r < 4; ++r) {
            const int pt = pg * 16 + (l >> 4) * 4 + r;
            ctxT[dglob * 33 + pt] = acc[nt][r] + bias + bfu(res[nt][r]);
        }
    }
    __syncthreads();
    {
        const int p = t & 31;
        const int ch0 = t >> 5;
        #pragma unroll
        for (int i = 0; i < 16; ++i) {
            const int ch = ch0 + (i << 3);
            out[(size_t)ch * NPTS + n0 + p] = ctxT[ch * 33 + p];
        }
    }
}

extern "C" void kernel_launch(void* const* d_in, const int* in_sizes, int n_in,
                              void* d_out, int out_size, void* d_ws, size_t ws_size,
                              hipStream_t stream) {
    const float* spa = (const float*)d_in[0];
    const float* spe = (const float*)d_in[1];
    const int* idx   = (const int*)d_in[2];
    const float* WQa = (const float*)d_in[3];
    const float* WKa = (const float*)d_in[4];
    const float* WVa = (const float*)d_in[5];
    const float* bVa = (const float*)d_in[6];
    const float* WQe = (const float*)d_in[7];
    const float* WKe = (const float*)d_in[8];
    const float* WVe = (const float*)d_in[9];
    const float* bVe = (const float*)d_in[10];
    float* out = (float*)d_out;

    char* ws = (char*)d_ws;
    unsigned short* featT = (unsigned short*)(ws);              // 16.78 MB bf16 [N][128]
    unsigned char*  qeff8 = (unsigned char*)(ws + 16777216);    // 8.39 MB fp8 [N][128]
    unsigned char*  sTb8  = (unsigned char*)(ws + 25165824);    // 8.39 MB fp8 [N][128]
    unsigned short* Mt    = (unsigned short*)(ws + 33554432);   // 16 KB bf16 [2][64][64]
    unsigned short* WVb   = (unsigned short*)(ws + 33570816);   // 16 KB bf16 [2][64][64]
    unsigned char*  featQ = (unsigned char*)(ws + 33587200);    // 8.39 MB fp8 [N][128]

    k_matM<<<10, 256, 0, stream>>>(WQa, WKa, WQe, WKe, WVa, WVe, Mt, WVb);
    k_prep<<<1024, 256, 0, stream>>>(spa, spe, Mt, featT, featQ, qeff8);
    k_attn<<<16384, 256, 0, stream>>>(featQ, qeff8, idx, sTb8);
    k_out<<<2048, 256, 0, stream>>>(sTb8, featT, WVb, bVa, bVe, out);
}

// Round 17
// 66.247 us; speedup vs baseline: 1.0569x; 1.0569x over previous
//
#include <hip/hip_runtime.h>

#define NPTS 65536

__device__ __forceinline__ float bf_lo(unsigned u) { return __uint_as_float(u << 16); }
__device__ __forceinline__ float bf_hi(unsigned u) { return __uint_as_float(u & 0xFFFF0000u); }
__device__ __forceinline__ unsigned short f2bf(float f) {      // RNE round
    unsigned u = __float_as_uint(f);
    return (unsigned short)((u + 0x7FFFu + ((u >> 16) & 1u)) >> 16);
}
__device__ __forceinline__ float bfu(unsigned short us) {
    return __uint_as_float(((unsigned)us) << 16);
}
__device__ __forceinline__ unsigned pktrunc(float a, float b) { // truncate pair pack
    return (__float_as_uint(a) >> 16) | (__float_as_uint(b) & 0xFFFF0000u);
}
__device__ __forceinline__ void unpack8(uint4 v, float* o) {
    o[0] = bf_lo(v.x); o[1] = bf_hi(v.x); o[2] = bf_lo(v.y); o[3] = bf_hi(v.y);
    o[4] = bf_lo(v.z); o[5] = bf_hi(v.z); o[6] = bf_lo(v.w); o[7] = bf_hi(v.w);
}
#if __has_builtin(__builtin_amdgcn_fdot2_f32_bf16)
typedef __bf16 bf16x2 __attribute__((ext_vector_type(2)));
__device__ __forceinline__ float dot2acc(unsigned a, unsigned b, float c) {
    return __builtin_amdgcn_fdot2_f32_bf16(__builtin_bit_cast(bf16x2, a),
                                           __builtin_bit_cast(bf16x2, b), c, false);
}
#else
__device__ __forceinline__ float dot2acc(unsigned a, unsigned b, float c) {
    return c + bf_lo(a) * bf_lo(b) + bf_hi(a) * bf_hi(b);
}
#endif
#if __has_builtin(__builtin_amdgcn_rcpf)
__device__ __forceinline__ float fastrcp(float x) { return __builtin_amdgcn_rcpf(x); }
#else
__device__ __forceinline__ float fastrcp(float x) { return 1.0f / x; }
#endif

// ---- fp8 e4m3 pack/unpack (HW cvt). Fallback: bf16-gather path (R14). ------
#if __has_builtin(__builtin_amdgcn_cvt_pk_f32_fp8) && __has_builtin(__builtin_amdgcn_cvt_pk_fp8_f32)
#define USE_FP8 1
typedef float floatx2 __attribute__((ext_vector_type(2)));
__device__ __forceinline__ void unpk_fp8_u32(unsigned u, float* o) {
    floatx2 lo = __builtin_amdgcn_cvt_pk_f32_fp8((int)u, false);
    floatx2 hi = __builtin_amdgcn_cvt_pk_f32_fp8((int)u, true);
    o[0] = lo[0]; o[1] = lo[1]; o[2] = hi[0]; o[3] = hi[1];
}
__device__ __forceinline__ unsigned pk_fp8_4(float a, float b, float c, float d) {
    int v = __builtin_amdgcn_cvt_pk_fp8_f32(a, b, 0, false);
    v = __builtin_amdgcn_cvt_pk_fp8_f32(c, d, v, true);
    return (unsigned)v;
}
#else
#define USE_FP8 0
#endif

typedef __attribute__((ext_vector_type(8))) short short8;     // bf16x8 frag
typedef __attribute__((ext_vector_type(4))) float f32x4;      // acc frag

// -------- Kernel 1: Mt[which][e][c] = bf16((WQ^T WK)[c][e]); WVb = bf16(WV) --
__global__ __launch_bounds__(256) void k_matM(const float* __restrict__ WQa,
                                              const float* __restrict__ WKa,
                                              const float* __restrict__ WQe,
                                              const float* __restrict__ WKe,
                                              const float* __restrict__ WVa,
                                              const float* __restrict__ WVe,
                                              unsigned short* __restrict__ Mt,
                                              unsigned short* __restrict__ WVb) {
    const int t = threadIdx.x;
    if (blockIdx.x >= 8) {            // WV -> bf16 table
        const int which = blockIdx.x - 8;
        const float* WV = which ? WVe : WVa;
        unsigned short* dst = WVb + which * 4096;
        #pragma unroll
        for (int i = 0; i < 16; ++i) dst[t + i * 256] = f2bf(WV[t + i * 256]);
        return;
    }
    __shared__ float WKs[4096];       // full WK, row-major [d][e]
    __shared__ float WQs[64][16];     // WQ columns c0..c0+15
    const int which = blockIdx.x >> 2;
    const int c0 = (blockIdx.x & 3) * 16;
    const float* WQ = which ? WQe : WQa;
    const float* WK = which ? WKe : WKa;
    #pragma unroll
    for (int i = 0; i < 16; ++i) WKs[t + i * 256] = WK[t + i * 256];
    #pragma unroll
    for (int i = 0; i < 4; ++i) {
        const int id = t + i * 256;
        WQs[id >> 4][id & 15] = WQ[(id >> 4) * 64 + c0 + (id & 15)];
    }
    __syncthreads();
    const int cc = t >> 4;            // c = c0+cc
    const int eg = t & 15;            // e = eg*4 + j
    float a0 = 0.f, a1 = 0.f, a2 = 0.f, a3 = 0.f;
    #pragma unroll
    for (int d = 0; d < 64; ++d) {
        const float wq = WQs[d][cc];
        const float4 wk = *reinterpret_cast<const float4*>(&WKs[d * 64 + eg * 4]);
        a0 += wq * wk.x; a1 += wq * wk.y; a2 += wq * wk.z; a3 += wq * wk.w;
    }
    const int c = c0 + cc;
    Mt[which * 4096 + (eg * 4 + 0) * 64 + c] = f2bf(a0);
    Mt[which * 4096 + (eg * 4 + 1) * 64 + c] = f2bf(a1);
    Mt[which * 4096 + (eg * 4 + 2) * 64 + c] = f2bf(a2);
    Mt[which * 4096 + (eg * 4 + 3) * 64 + c] = f2bf(a3);
}

// -------- Kernel 2: pack featT bf16 (+featQ fp8) + qeff via MFMA GEMM --------
__global__ __launch_bounds__(256) void k_prep(const float* __restrict__ spa,
                                              const float* __restrict__ spe,
                                              const unsigned short* __restrict__ Mt,
                                              unsigned short* __restrict__ featT,
                                              unsigned char* __restrict__ featQ,
                                              unsigned short* __restrict__ qeff) {
    __shared__ unsigned short tb[64][136];   // 17408 B
    __shared__ unsigned short ml[2][64][72]; // 18432 B
    const int n0 = blockIdx.x * 64;
    const int t = threadIdx.x;
    // ---- phase 0: stage Mt (16 KB) into LDS
    #pragma unroll
    for (int i = 0; i < 4; ++i) {
        const int id = t + i * 256;
        const int which = id >> 9;
        const int row = (id >> 3) & 63;
        const int q = id & 7;
        *reinterpret_cast<uint4*>(&ml[which][row][q * 8]) =
            *reinterpret_cast<const uint4*>(Mt + which * 4096 + row * 64 + q * 8);
    }
    // ---- phase 1: coalesced column loads -> bf16 tile, channel-PAIR packed
    {
        const int p = t & 63;
        const int c0 = 2 * (t >> 6);          // 0,2,4,6
        #pragma unroll
        for (int i = 0; i < 16; ++i) {
            const int c = c0 + 8 * i;
            const float v0 = (c < 64) ? spa[c * NPTS + n0 + p]
                                      : spe[(c - 64) * NPTS + n0 + p];
            const float v1 = (c + 1 < 64) ? spa[(c + 1) * NPTS + n0 + p]
                                          : spe[(c + 1 - 64) * NPTS + n0 + p];
            *reinterpret_cast<unsigned*>(&tb[p][c]) =
                (unsigned)f2bf(v0) | ((unsigned)f2bf(v1) << 16);
        }
    }
    __syncthreads();
    // ---- phase 2: featT (bf16) + featQ (fp8) writeback
    {
        const int pt = t >> 2;
        const int q = t & 3;
        const uint4* src = reinterpret_cast<const uint4*>(&tb[pt][q * 32]);
        const uint4 s0 = src[0], s1 = src[1], s2 = src[2], s3 = src[3];
        uint4* dst = reinterpret_cast<uint4*>(featT + (size_t)(n0 + pt) * 128 + q * 32);
        dst[0] = s0; dst[1] = s1; dst[2] = s2; dst[3] = s3;
#if USE_FP8
        unsigned o0 = pk_fp8_4(bf_lo(s0.x), bf_hi(s0.x), bf_lo(s0.y), bf_hi(s0.y));
        unsigned o1 = pk_fp8_4(bf_lo(s0.z), bf_hi(s0.z), bf_lo(s0.w), bf_hi(s0.w));
        unsigned o2 = pk_fp8_4(bf_lo(s1.x), bf_hi(s1.x), bf_lo(s1.y), bf_hi(s1.y));
        unsigned o3 = pk_fp8_4(bf_lo(s1.z), bf_hi(s1.z), bf_lo(s1.w), bf_hi(s1.w));
        unsigned o4 = pk_fp8_4(bf_lo(s2.x), bf_hi(s2.x), bf_lo(s2.y), bf_hi(s2.y));
        unsigned o5 = pk_fp8_4(bf_lo(s2.z), bf_hi(s2.z), bf_lo(s2.w), bf_hi(s2.w));
        unsigned o6 = pk_fp8_4(bf_lo(s3.x), bf_hi(s3.x), bf_lo(s3.y), bf_hi(s3.y));
        unsigned o7 = pk_fp8_4(bf_lo(s3.z), bf_hi(s3.z), bf_lo(s3.w), bf_hi(s3.w));
        uint4* qd = reinterpret_cast<uint4*>(featQ + (size_t)(n0 + pt) * 128 + q * 32);
        qd[0] = make_uint4(o0, o1, o2, o3);
        qd[1] = make_uint4(o4, o5, o6, o7);
#endif
    }
    // ---- phase 3: qeff GEMM via MFMA
    const int w = t >> 6;
    const int l = t & 63;
    const int lrow = l & 15;
    const int lk8 = (l >> 4) * 8;
    short8 afr[2][2];
    #pragma unroll
    for (int half = 0; half < 2; ++half)
        #pragma unroll
        for (int kc = 0; kc < 2; ++kc)
            afr[half][kc] = __builtin_bit_cast(short8,
                *reinterpret_cast<const uint4*>(&tb[w * 16 + lrow][half * 64 + kc * 32 + lk8]));
    f32x4 acc[8];
    #pragma unroll
    for (int et = 0; et < 8; ++et) acc[et] = (f32x4){0.f, 0.f, 0.f, 0.f};
    #pragma unroll
    for (int et = 0; et < 8; ++et) {
        const int which = et >> 2;
        const int el = (et & 3) * 16 + lrow;
        #pragma unroll
        for (int kc = 0; kc < 2; ++kc) {
            const short8 bfr = __builtin_bit_cast(short8,
                *reinterpret_cast<const uint4*>(&ml[which][el][kc * 32 + lk8]));
            acc[et] = __builtin_amdgcn_mfma_f32_16x16x32_bf16(afr[which][kc], bfr, acc[et], 0, 0, 0);
        }
    }
    #pragma unroll
    for (int et = 0; et < 8; ++et) {
        #pragma unroll
        for (int r = 0; r < 4; ++r) {
            const int n = n0 + w * 16 + (l >> 4) * 4 + r;
            qeff[(size_t)n * 128 + et * 16 + lrow] = f2bf(acc[et][r]);
        }
    }
}

// ---------------- Kernel 3: attention (1 wave = 1 point, lane = k*4+c4) ------
__global__ __launch_bounds__(256) void k_attn(const unsigned short* __restrict__ featT,
                                              const unsigned char* __restrict__ featQ,
                                              const unsigned short* __restrict__ qeff,
                                              const int* __restrict__ idx,
                                              unsigned short* __restrict__ sTb) {
    __shared__ unsigned red[4][16][68];   // 17408 B
    const int wave = threadIdx.x >> 6;
    const int lane = threadIdx.x & 63;
    const int n = blockIdx.x * 4 + wave;
    const int k = lane >> 2;          // neighbor owned by this lane
    const int c4 = lane & 3;          // channel quarter (16 channels)

    const int j = idx[n * 16 + k];    // 4 lanes same addr -> broadcast
    float xa[16], xe[16];
    unsigned bxa[8], bxe[8];          // packed bf16 pairs for dot2 scores
#if USE_FP8
    const uint4* fq = reinterpret_cast<const uint4*>(featQ + (size_t)j * 128);
    const uint4 FA = fq[c4], FE = fq[4 + c4];      // 16 fp8 each
    unpk_fp8_u32(FA.x, xa);      unpk_fp8_u32(FA.y, xa + 4);
    unpk_fp8_u32(FA.z, xa + 8);  unpk_fp8_u32(FA.w, xa + 12);
    unpk_fp8_u32(FE.x, xe);      unpk_fp8_u32(FE.y, xe + 4);
    unpk_fp8_u32(FE.z, xe + 8);  unpk_fp8_u32(FE.w, xe + 12);
    #pragma unroll
    for (int i = 0; i < 8; ++i) {     // exact: fp8 mantissa fits bf16
        bxa[i] = pktrunc(xa[2*i], xa[2*i + 1]);
        bxe[i] = pktrunc(xe[2*i], xe[2*i + 1]);
    }
#else
    const uint4* fx = reinterpret_cast<const uint4*>(featT + (size_t)j * 128);
    const uint4 A0 = fx[2*c4],     A1 = fx[2*c4 + 1];
    const uint4 E0 = fx[8 + 2*c4], E1 = fx[8 + 2*c4 + 1];
    unpack8(A0, xa); unpack8(A1, xa + 8);
    unpack8(E0, xe); unpack8(E1, xe + 8);
    bxa[0] = A0.x; bxa[1] = A0.y; bxa[2] = A0.z; bxa[3] = A0.w;
    bxa[4] = A1.x; bxa[5] = A1.y; bxa[6] = A1.z; bxa[7] = A1.w;
    bxe[0] = E0.x; bxe[1] = E0.y; bxe[2] = E0.z; bxe[3] = E0.w;
    bxe[4] = E1.x; bxe[5] = E1.y; bxe[6] = E1.z; bxe[7] = E1.w;
#endif
    const uint4* qx = reinterpret_cast<const uint4*>(qeff + (size_t)n * 128);
    const uint4 QA0 = qx[2*c4],     QA1 = qx[2*c4 + 1];
    const uint4 QE0 = qx[8 + 2*c4], QE1 = qx[8 + 2*c4 + 1];

    // scores: spa att = q_spa . x_spe ; spe att = q_spe . x_spa
    float pa = 0.f, pe = 0.f;
    pa = dot2acc(QA0.x, bxe[0], pa); pa = dot2acc(QA0.y, bxe[1], pa);
    pa = dot2acc(QA0.z, bxe[2], pa); pa = dot2acc(QA0.w, bxe[3], pa);
    pa = dot2acc(QA1.x, bxe[4], pa); pa = dot2acc(QA1.y, bxe[5], pa);
    pa = dot2acc(QA1.z, bxe[6], pa); pa = dot2acc(QA1.w, bxe[7], pa);
    pe = dot2acc(QE0.x, bxa[0], pe); pe = dot2acc(QE0.y, bxa[1], pe);
    pe = dot2acc(QE0.z, bxa[2], pe); pe = dot2acc(QE0.w, bxa[3], pe);
    pe = dot2acc(QE1.x, bxa[4], pe); pe = dot2acc(QE1.y, bxa[5], pe);
    pe = dot2acc(QE1.z, bxa[6], pe); pe = dot2acc(QE1.w, bxa[7], pe);
    pa += __shfl_xor(pa, 1); pa += __shfl_xor(pa, 2);   // reduce over c4
    pe += __shfl_xor(pe, 1); pe += __shfl_xor(pe, 2);
    // |score| small by construction -> exp w/o max-sub
    const float ea = __expf(pa * 0.125f);
    const float ee = __expf(pe * 0.125f);
    float da = ea, de = ee;
    #pragma unroll
    for (int m = 4; m < 64; m <<= 1) {  // sum over the 16 k, each once
        da += __shfl_xor(da, m);
        de += __shfl_xor(de, m);
    }
    const float wA = ea * fastrcp(da);
    const float wB = ee * fastrcp(de);

    // packed truncate-to-bf16 pairs; col j = channels (2j, 2j+1)
    unsigned pA[8], pB[8];
    #pragma unroll
    for (int i = 0; i < 8; ++i) {
        pA[i] = pktrunc(wA * xe[2*i], wA * xe[2*i + 1]);   // ctx_spa from spe
        pB[i] = pktrunc(wB * xa[2*i], wB * xa[2*i + 1]);   // ctx_spe from spa
    }
    {
        uint4* wa4 = reinterpret_cast<uint4*>(&red[wave][k][c4 * 8]);
        wa4[0] = make_uint4(pA[0], pA[1], pA[2], pA[3]);
        wa4[1] = make_uint4(pA[4], pA[5], pA[6], pA[7]);
        uint4* wb4 = reinterpret_cast<uint4*>(&red[wave][k][32 + c4 * 8]);
        wb4[0] = make_uint4(pB[0], pB[1], pB[2], pB[3]);
        wb4[1] = make_uint4(pB[4], pB[5], pB[6], pB[7]);
    }
    asm volatile("s_waitcnt lgkmcnt(0)" ::: "memory");  // wave-internal fence
    float s0 = 0.f, s1 = 0.f;
    #pragma unroll
    for (int kk = 0; kk < 16; ++kk) {
        const unsigned v = red[wave][kk][lane];
        s0 += __uint_as_float(v << 16);
        s1 += __uint_as_float(v & 0xFFFF0000u);
    }
    reinterpret_cast<unsigned*>(sTb + (size_t)n * 128)[lane] =
        (unsigned)f2bf(s0) | ((unsigned)f2bf(s1) << 16);
}

// ---------------- Kernel 4: ctx = WV*s + b via MFMA, + residual, write -------
__global__ __launch_bounds__(256, 4) void k_out(const unsigned short* __restrict__ sTb,
                                                const unsigned short* __restrict__ featT,
                                                const unsigned short* __restrict__ WVb,
                                                const float* __restrict__ bVa,
                                                const float* __restrict__ bVe,
                                                float* __restrict__ out) {
    __shared__ char smem_raw[27136];
    unsigned short* stile = reinterpret_cast<unsigned short*>(smem_raw);         // [32][136]
    unsigned short* wvl = reinterpret_cast<unsigned short*>(smem_raw + 8704);    // [2][64][72]
    float* ctxT = reinterpret_cast<float*>(smem_raw);                            // [128][33] overlay
    const int n0 = blockIdx.x * 32;
    const int t = threadIdx.x;
    const int w = t >> 6;
    const int l = t & 63;
    const int half = w >> 1;
    const int pg = w & 1;
    const int lrow = l & 15;
    const int lk8 = (l >> 4) * 8;
    unsigned short res[4][4];
    #pragma unroll
    for (int nt = 0; nt < 4; ++nt)
        #pragma unroll
        for (int r = 0; r < 4; ++r) {
            const int pt = pg * 16 + (l >> 4) * 4 + r;
            res[nt][r] = featT[(size_t)(n0 + pt) * 128 + half * 64 + nt * 16 + lrow];
        }
    #pragma unroll
    for (int i = 0; i < 2; ++i) {
        const int id = t + i * 256;
        const int pt = id >> 4;
        const int q = id & 15;
        *reinterpret_cast<uint4*>(stile + pt * 136 + q * 8) =
            *reinterpret_cast<const uint4*>(sTb + (size_t)(n0 + pt) * 128 + q * 8);
    }
    #pragma unroll
    for (int i = 0; i < 4; ++i) {
        const int id = t + i * 256;
        const int which = id >> 9;
        const int row = (id >> 3) & 63;
        const int q = id & 7;
        *reinterpret_cast<uint4*>(wvl + which * 4608 + row * 72 + q * 8) =
            *reinterpret_cast<const uint4*>(WVb + which * 4096 + row * 64 + q * 8);
    }
    __syncthreads();
    short8 afr[2];
    #pragma unroll
    for (int kc = 0; kc < 2; ++kc)
        afr[kc] = __builtin_bit_cast(short8,
            *reinterpret_cast<const uint4*>(stile + (pg * 16 + lrow) * 136 + half * 64 + kc * 32 + lk8));
    const unsigned short* wt = wvl + half * 4608;
    const float* bV = half ? bVe : bVa;
    f32x4 acc[4];
    #pragma unroll
    for (int nt = 0; nt < 4; ++nt) {
        acc[nt] = (f32x4){0.f, 0.f, 0.f, 0.f};
        #pragma unroll
        for (int kc = 0; kc < 2; ++kc) {
            const short8 bfr = __builtin_bit_cast(short8,
                *reinterpret_cast<const uint4*>(wt + (nt * 16 + lrow) * 72 + kc * 32 + lk8));
            acc[nt] = __builtin_amdgcn_mfma_f32_16x16x32_bf16(afr[kc], bfr, acc[nt], 0, 0, 0);
        }
    }
    __syncthreads();
    #pragma unroll
    for (int nt = 0; nt < 4; ++nt) {
        const int d = nt * 16 + lrow;
        const int dglob = half * 64 + d;
        const float bias = bV[d];
        #pragma unroll
        for (int r = 0; r < 4; ++r) {
            const int pt = pg * 16 + (l >> 4) * 4 + r;
            ctxT[dglob * 33 + pt] = acc[nt][r] + bias + bfu(res[nt][r]);
        }
    }
    __syncthreads();
    {
        const int p = t & 31;
        const int ch0 = t >> 5;
        #pragma unroll
        for (int i = 0; i < 16; ++i) {
            const int ch = ch0 + (i << 3);
            out[(size_t)ch * NPTS + n0 + p] = ctxT[ch * 33 + p];
        }
    }
}

extern "C" void kernel_launch(void* const* d_in, const int* in_sizes, int n_in,
                              void* d_out, int out_size, void* d_ws, size_t ws_size,
                              hipStream_t stream) {
    const float* spa = (const float*)d_in[0];
    const float* spe = (const float*)d_in[1];
    const int* idx   = (const int*)d_in[2];
    const float* WQa = (const float*)d_in[3];
    const float* WKa = (const float*)d_in[4];
    const float* WVa = (const float*)d_in[5];
    const float* bVa = (const float*)d_in[6];
    const float* WQe = (const float*)d_in[7];
    const float* WKe = (const float*)d_in[8];
    const float* WVe = (const float*)d_in[9];
    const float* bVe = (const float*)d_in[10];
    float* out = (float*)d_out;

    char* ws = (char*)d_ws;
    unsigned short* featT = (unsigned short*)(ws);              // 16.78 MB bf16 [N][128]
    unsigned short* qeff  = (unsigned short*)(ws + 16777216);   // 16.78 MB bf16 [N][128]
    unsigned short* sTb   = (unsigned short*)(ws + 33554432);   // 16.78 MB bf16 [N][128]
    unsigned short* Mt    = (unsigned short*)(ws + 50331648);   // 16 KB bf16 [2][64][64]
    unsigned short* WVb   = (unsigned short*)(ws + 50348032);   // 16 KB bf16 [2][64][64]
    unsigned char*  featQ = (unsigned char*)(ws + 50364416);    // 8.39 MB fp8 [N][128]

    k_matM<<<10, 256, 0, stream>>>(WQa, WKa, WQe, WKe, WVa, WVe, Mt, WVb);
    k_prep<<<1024, 256, 0, stream>>>(spa, spe, Mt, featT, featQ, qeff);
    k_attn<<<16384, 256, 0, stream>>>(featT, featQ, qeff, idx, sTb);
    k_out<<<2048, 256, 0, stream>>>(sTb, featT, WVb, bVa, bVe, out);
}